// Round 12
// baseline (7744.305 us; speedup 1.0000x reference)
//
#include <hip/hip_runtime.h>
#include <math.h>

// ---------------------------------------------------------------------------
// SpatioTemporalAutoEncoder: conv3d x2 -> ConvLSTM2D x3 -> conv3d_transpose x2
// All fp32. Layouts are the reference's NDHWC flattened row-major.
// ---------------------------------------------------------------------------

__device__ __forceinline__ float hsig(float x) {
    float y = 0.2f * x + 0.5f;
    return fminf(fmaxf(y, 0.f), 1.f);
}

// ---------------------------------------------------------------------------
// conv1: x (8,227,227,10,1) * w (11,11,1,1,128) stride (4,4,1) + b, relu
//   -> e1 (8,55,55,10,128)
// ---------------------------------------------------------------------------
__global__ __launch_bounds__(256) void k_conv1(const float* __restrict__ x,
                                               const float* __restrict__ w1,
                                               const float* __restrict__ b1,
                                               float* __restrict__ e1) {
    int bid = blockIdx.x;
    int ht = bid & 3; int tmp = bid >> 2;
    int w = tmp % 10; tmp /= 10;
    int d = tmp % 55; int n = tmp / 55;
    int h0 = ht * 16;

    __shared__ __align__(16) float patch[11][72];
    int tid = threadIdx.x;
    for (int idx = tid; idx < 11 * 71; idx += 256) {
        int j = idx % 71; int kd = idx / 71;
        int rr = d * 4 + kd; int cc = h0 * 4 + j;
        float v = 0.f;
        if (cc < 227) v = x[((n * 227 + rr) * 227 + cc) * 10 + w];
        patch[kd][j] = v;
    }
    __syncthreads();

    int co = tid & 127, pg = tid >> 7;
    float acc[8];
#pragma unroll
    for (int p = 0; p < 8; p++) acc[p] = 0.f;

    for (int kd = 0; kd < 11; kd++) {
        const float4* row = (const float4*)&patch[kd][pg * 32];
        float rr2[40];
#pragma unroll
        for (int q = 0; q < 10; q++) {
            float4 t4 = row[q];
            rr2[4 * q] = t4.x; rr2[4 * q + 1] = t4.y; rr2[4 * q + 2] = t4.z; rr2[4 * q + 3] = t4.w;
        }
        const float* wp = w1 + (kd * 11) * 128 + co;
#pragma unroll
        for (int kh = 0; kh < 11; kh++) {
            float wv = wp[kh * 128];
#pragma unroll
            for (int p = 0; p < 8; p++) acc[p] += rr2[p * 4 + kh] * wv;
        }
    }
    float bv = b1[co];
#pragma unroll
    for (int p = 0; p < 8; p++) {
        int h = h0 + pg * 8 + p;
        if (h < 55)
            e1[(((n * 55 + d) * 55 + h) * 10 + w) * 128 + co] = fmaxf(acc[p] + bv, 0.f);
    }
}

// ---------------------------------------------------------------------------
// conv2: e1 (8,55,55,10,128) * w (5,5,1,128,64) stride (2,2,1) + b, relu
//   -> e2 (8,26,26,10,64)
// R12 rewrite: grid ht(2)|w(10)|d(26)|n(8) = 4160 blocks (XCD-chunked: each
// XCD gets one full n => d-neighbor row reuse hits the same L2), 128 thr
// (co64 x pg2, h-halves within the ht half-range). 10KB LDS -> ~16 blk/CU.
// Division-free staging; 5-weight hoisted loads per 4-ci group; per-pg
// 16B-aligned float4 windows (base pg*12).
// ---------------------------------------------------------------------------
__global__ __launch_bounds__(128) void k_conv2(const float* __restrict__ e1,
                                               const float* __restrict__ w2,
                                               const float* __restrict__ b2,
                                               float* __restrict__ e2) {
    // XCD-chunked swizzle: 4160 = 8 * 520; each chunk of 520 = one n.
    int bid = (blockIdx.x & 7) * 520 + (blockIdx.x >> 3);
    int ht = bid & 1; int tmp = bid >> 1;
    int w = tmp % 10; tmp /= 10;
    int d = tmp % 26; int n = tmp / 26;
    int cb = ht * 26;  // global input-col base; local cols 0..28 used

    __shared__ __align__(16) float patch[5][16][32];
    int tid = threadIdx.x;
    int co = tid & 63, pg = tid >> 6;
    float bv = b2[co];
    float acc[7];
#pragma unroll
    for (int p = 0; p < 7; p++) acc[p] = bv;
    const int npg = (pg == 0) ? 7 : 6;  // h outputs: pg0 -> 7, pg1 -> 6

    for (int c0 = 0; c0 < 128; c0 += 16) {
        __syncthreads();
        // stage rows d*2+kr (5), local cols 0..28 (pad to 32 with zeros)
#pragma unroll
        for (int k = 0; k < 20; k++) {
            int idx = tid + k * 128;
            int ci = idx & 15;
            int col = (idx >> 4) & 31;
            int kr = idx >> 9;
            float v = 0.f;
            if (col < 29)
                v = e1[(((n * 55 + d * 2 + kr) * 55 + cb + col) * 10 + w) * 128 + c0 + ci];
            patch[kr][ci][col] = v;
        }
        __syncthreads();

        for (int kr = 0; kr < 5; kr++) {
            for (int ci0 = 0; ci0 < 16; ci0 += 4) {
                float wv[4][5];
#pragma unroll
                for (int u = 0; u < 4; u++) {
                    const float* wp = w2 + ((kr * 5) * 128 + c0 + ci0 + u) * 64 + co;
#pragma unroll
                    for (int kh = 0; kh < 5; kh++) wv[u][kh] = wp[kh * 128 * 64];
                }
#pragma unroll
                for (int u = 0; u < 4; u++) {
                    const float4* row = (const float4*)&patch[kr][ci0 + u][pg * 12];
                    float rr2[20];
#pragma unroll
                    for (int q = 0; q < 5; q++) {
                        float4 t4 = row[q];
                        rr2[4 * q] = t4.x; rr2[4 * q + 1] = t4.y;
                        rr2[4 * q + 2] = t4.z; rr2[4 * q + 3] = t4.w;
                    }
#pragma unroll
                    for (int kh = 0; kh < 5; kh++) {
                        float w_ = wv[u][kh];
#pragma unroll
                        for (int p = 0; p < 7; p++)
                            acc[p] += rr2[2 * p + kh + 2 * pg] * w_;
                    }
                }
            }
        }
    }
#pragma unroll
    for (int p = 0; p < 7; p++) {
        if (p < npg) {
            int h = ht * 13 + pg * 7 + p;
            e2[(((n * 26 + d) * 26 + h) * 10 + w) * 64 + co] = fmaxf(acc[p], 0.f);
        }
    }
}

// ---------------------------------------------------------------------------
// x-conv for ConvLSTM: 3x3 SAME conv over 26x10 frames, batched over 208
// frames. in: [fr = n*26+t][r][c][CIN]; out xz: [t*8+n][r][c][COUT] (+bias)
// ---------------------------------------------------------------------------
template <int CIN, int COUT>
__global__ __launch_bounds__(COUT) void k_xconv(const float* __restrict__ in,
                                                const float* __restrict__ wx,
                                                const float* __restrict__ bias,
                                                float* __restrict__ xz) {
    int bid = blockIdx.x;
    int r = bid % 26; int fr = bid / 26;
    int n = fr / 26, t = fr % 26;

    __shared__ __align__(16) float patch[3][CIN][12];
    int tid = threadIdx.x;
    const float* inf = in + (size_t)fr * (26 * 10 * CIN);
    for (int idx = tid; idx < 3 * 12 * CIN; idx += COUT) {
        int ci = idx % CIN; int t2 = idx / CIN;
        int col = t2 % 12; int kr = t2 / 12;
        int rr = r - 1 + kr; int cc = col - 1;
        float v = 0.f;
        if (rr >= 0 && rr < 26 && cc >= 0 && cc < 10)
            v = inf[(rr * 10 + cc) * CIN + ci];
        patch[kr][ci][col] = v;
    }
    __syncthreads();

    int co = tid;
    float bv = bias[co];
    float acc[10];
#pragma unroll
    for (int c = 0; c < 10; c++) acc[c] = bv;

    for (int kr = 0; kr < 3; kr++) {
        for (int ci0 = 0; ci0 < CIN; ci0 += 4) {
            float wv[4][3];
#pragma unroll
            for (int u = 0; u < 4; u++) {
                const float* wp = wx + ((kr * 3) * CIN + ci0 + u) * COUT + co;
#pragma unroll
                for (int kc = 0; kc < 3; kc++) wv[u][kc] = wp[kc * CIN * COUT];
            }
#pragma unroll
            for (int u = 0; u < 4; u++) {
                const float4* row = (const float4*)&patch[kr][ci0 + u][0];
                float rr2[12];
#pragma unroll
                for (int q = 0; q < 3; q++) {
                    float4 t4 = row[q];
                    rr2[4 * q] = t4.x; rr2[4 * q + 1] = t4.y;
                    rr2[4 * q + 2] = t4.z; rr2[4 * q + 3] = t4.w;
                }
#pragma unroll
                for (int kc = 0; kc < 3; kc++) {
                    float w_ = wv[u][kc];
#pragma unroll
                    for (int c = 0; c < 10; c++) acc[c] += rr2[c + kc] * w_;
                }
            }
        }
    }
    float* outp = xz + ((size_t)(t * 8 + n) * 260 + r * 10) * COUT + co;
#pragma unroll
    for (int c = 0; c < 10; c++) outp[c * COUT] = acc[c];
}

// ---------------------------------------------------------------------------
// Flag reset (before each LSTM layer): flags[b*26+r] = steps completed.
// ---------------------------------------------------------------------------
__global__ void k_rst(int* __restrict__ f) {
    if (threadIdx.x < 208)
        __hip_atomic_store(f + threadIdx.x, 0, __ATOMIC_RELAXED,
                           __HIP_MEMORY_SCOPE_AGENT);
}

// ---------------------------------------------------------------------------
// ConvLSTM layer, flag-skew pipeline, spill-free scheduling. (R11, passing.)
// RELEASE flag publish; agent-scope atomic halo/publish; dedicated y buffers;
// no per-thread array live across __syncthreads() (64-VGPR cap @1024 thr).
// ---------------------------------------------------------------------------
template <int F, int QS>
__global__ __launch_bounds__(4 * F * QS) void k_lstm(const float* __restrict__ xz,
                                                     const float* __restrict__ wh,
                                                     float* __restrict__ y,
                                                     int* __restrict__ flags) {
    constexpr int C4 = 4 * F;
    constexpr int NT = 4 * F * QS;
    constexpr int CQ = F / QS;
    int bid = blockIdx.x;
    int r = bid % 26; int b = bid / 26;
    int tid = threadIdx.x;
    int co = tid & (C4 - 1);
    int q = tid / C4;
    int ci0 = q * CQ;

    __shared__ __align__(16) float patch[3][F][12];
    __shared__ float zpart[QS][10][C4];

    for (int i = tid; i < 3 * F * 12; i += NT) ((float*)patch)[i] = 0.f;
    __syncthreads();

    float creg = 0.f;
    int gc = tid / F, gf = tid % F;
    int* fl = flags + b * 26;

    for (int t = 0; t < 26; t++) {
        if (t > 0) {
            if (tid < 2) {
                int nb = (tid == 0) ? r - 1 : r + 1;
                if (nb >= 0 && nb < 26) {
                    while (__hip_atomic_load(fl + nb, __ATOMIC_RELAXED,
                                             __HIP_MEMORY_SCOPE_AGENT) < t)
                        __builtin_amdgcn_s_sleep(1);
                }
            }
            __syncthreads();

            for (int i = tid; i < 2 * 10 * F; i += NT) {
                int ci = i % F; int t2 = i / F;
                int col = t2 % 10; int s = t2 / 10;
                int kr = 2 * s; int rr = r - 1 + kr;
                float v = 0.f;
                if (rr >= 0 && rr < 26)
                    v = __hip_atomic_load(
                        &y[((((size_t)b * 26 + (t - 1)) * 26 + rr) * 10 + col) * F + ci],
                        __ATOMIC_RELAXED, __HIP_MEMORY_SCOPE_AGENT);
                patch[kr][ci][col + 1] = v;
            }
            __syncthreads();
        }

        float acc[10];
        if (q == 0) {
            const float* xp = xz + ((size_t)(t * 8 + b) * 260 + r * 10) * C4 + co;
#pragma unroll
            for (int c = 0; c < 10; c++) acc[c] = xp[c * C4];
        } else {
#pragma unroll
            for (int c = 0; c < 10; c++) acc[c] = 0.f;
        }

        if (t > 0) {
            const int krseq[3] = {1, 0, 2};
            for (int kk = 0; kk < 3; kk++) {
                const int kr = krseq[kk];
                for (int cu = 0; cu < CQ; cu += 4) {
                    float wv[4][3];
#pragma unroll
                    for (int u = 0; u < 4; u++) {
                        const float* wp = wh + ((kr * 3) * F + ci0 + cu + u) * C4 + co;
#pragma unroll
                        for (int kc = 0; kc < 3; kc++) wv[u][kc] = wp[kc * F * C4];
                    }
#pragma unroll
                    for (int u = 0; u < 4; u++) {
                        const float4* row = (const float4*)&patch[kr][ci0 + cu + u][0];
                        float rr2[12];
#pragma unroll
                        for (int v4 = 0; v4 < 3; v4++) {
                            float4 t4 = row[v4];
                            rr2[4 * v4] = t4.x; rr2[4 * v4 + 1] = t4.y;
                            rr2[4 * v4 + 2] = t4.z; rr2[4 * v4 + 3] = t4.w;
                        }
#pragma unroll
                        for (int kc = 0; kc < 3; kc++) {
                            float w_ = wv[u][kc];
#pragma unroll
                            for (int c = 0; c < 10; c++) acc[c] += rr2[c + kc] * w_;
                        }
                    }
                }
            }
        }

#pragma unroll
        for (int c = 0; c < 10; c++) zpart[q][c][co] = acc[c];
        __syncthreads();

        if (tid < 10 * F) {
            float zi = 0.f, zf = 0.f, zg = 0.f, zo = 0.f;
#pragma unroll
            for (int qq = 0; qq < QS; qq++) {
                zi += zpart[qq][gc][gf];
                zf += zpart[qq][gc][F + gf];
                zg += zpart[qq][gc][2 * F + gf];
                zo += zpart[qq][gc][3 * F + gf];
            }
            float cn = hsig(zf) * creg + hsig(zi) * tanhf(zg);
            float hn = hsig(zo) * tanhf(cn);
            creg = cn;
            __hip_atomic_store(
                &y[((((size_t)b * 26 + t) * 26 + r) * 10 + gc) * F + gf], hn,
                __ATOMIC_RELAXED, __HIP_MEMORY_SCOPE_AGENT);
            patch[1][gf][gc + 1] = hn;
        }
        __syncthreads();

        if (tid == 0)
            __hip_atomic_store(fl + r, t + 1, __ATOMIC_RELEASE,
                               __HIP_MEMORY_SCOPE_AGENT);
    }
}

// ---------------------------------------------------------------------------
// deconv1: h3 (8,26,26,10,64) *T w (5,5,1,64,128) stride (2,2,1) + b, relu
//   -> d1 (8,55,55,10,128)
// ---------------------------------------------------------------------------
__global__ __launch_bounds__(256) void k_deconv1(const float* __restrict__ h3,
                                                 const float* __restrict__ dw,
                                                 const float* __restrict__ db,
                                                 float* __restrict__ out) {
    int bid = blockIdx.x;
    int ht = bid & 1; int tmp = bid >> 1;
    int w = tmp % 10; tmp /= 10;
    int od = tmp % 55; int n = tmp / 55;

    __shared__ __align__(16) float patch[3][64][24];
    int tid = threadIdx.x;
    int odd = od & 1;
    int id0 = odd ? (od - 3) / 2 : od / 2 - 2;
    int ihb = ht * 16 - 2;
    for (int idx = tid; idx < 3 * 20 * 64; idx += 256) {
        int ci = idx & 63; int t2 = idx >> 6;
        int j = t2 % 20; int s = t2 / 20;
        int id = id0 + s; int ih = ihb + j;
        float v = 0.f;
        if (id >= 0 && id < 26 && ih >= 0 && ih < 26)
            v = h3[((((size_t)n * 26 + id) * 26 + ih) * 10 + w) * 64 + ci];
        patch[s][ci][j] = v;
    }
    __syncthreads();

    int co = tid & 127, pg = tid >> 7;
    float acc[16];
#pragma unroll
    for (int p = 0; p < 16; p++) acc[p] = 0.f;

    int nslot = odd ? 2 : 3;
    for (int s = 0; s < nslot; s++) {
        int kd = odd ? (1 + 2 * s) : 2 * s;
        for (int ci = 0; ci < 64; ci++) {
            const float* pr = &patch[s][ci][pg * 8];
            float rr2[10];
            {
                float4 t0 = *(const float4*)pr;
                float4 t1 = *(const float4*)(pr + 4);
                float2 t2v = *(const float2*)(pr + 8);
                rr2[0] = t0.x; rr2[1] = t0.y; rr2[2] = t0.z; rr2[3] = t0.w;
                rr2[4] = t1.x; rr2[5] = t1.y; rr2[6] = t1.z; rr2[7] = t1.w;
                rr2[8] = t2v.x; rr2[9] = t2v.y;
            }
            const float* wp = dw + ((kd * 5) * 64 + ci) * 128 + co;
#pragma unroll
            for (int kh = 0; kh < 5; kh++) {
                float wv = wp[kh * 64 * 128];
                const int po = kh & 1;
                const int rbase = (kh + po) >> 1;
#pragma unroll
                for (int jj = 0; jj < 8; jj++)
                    acc[po + 2 * jj] += rr2[rbase + jj] * wv;
            }
        }
    }
    float bv = db[co];
#pragma unroll
    for (int p = 0; p < 16; p++) {
        int oh = ht * 32 + pg * 16 + p;
        if (oh < 55)
            out[((((size_t)n * 55 + od) * 55 + oh) * 10 + w) * 128 + co] =
                fmaxf(acc[p] + bv, 0.f);
    }
}

// ---------------------------------------------------------------------------
// deconv2 stage A (per batch n): D[k][pix] = dot(d1n[pix][0:128], dw[k][0:128])
// ---------------------------------------------------------------------------
__global__ __launch_bounds__(256) void k_dc2_gemm(const float* __restrict__ d1n,
                                                  const float* __restrict__ dw,
                                                  float* __restrict__ Dn) {
    int pix = blockIdx.x * 256 + threadIdx.x;
    bool act = pix < 30250;
    int khalf = blockIdx.y;

    float a[128];
    const float* ap = d1n + (size_t)(act ? pix : 0) * 128;
#pragma unroll
    for (int i = 0; i < 32; i++) {
        float4 v = ((const float4*)ap)[i];
        a[4 * i] = v.x; a[4 * i + 1] = v.y; a[4 * i + 2] = v.z; a[4 * i + 3] = v.w;
    }

    int k0 = khalf * 61;
    int kn = 61 - khalf;
    for (int kk = 0; kk < kn; kk++) {
        int k = k0 + kk;
        const float* wp = dw + k * 128;
        float acc0 = 0.f, acc1 = 0.f, acc2 = 0.f, acc3 = 0.f;
#pragma unroll
        for (int i = 0; i < 32; i++) {
            acc0 += a[4 * i + 0] * wp[4 * i + 0];
            acc1 += a[4 * i + 1] * wp[4 * i + 1];
            acc2 += a[4 * i + 2] * wp[4 * i + 2];
            acc3 += a[4 * i + 3] * wp[4 * i + 3];
        }
        if (act) Dn[k * 30250 + pix] = (acc0 + acc1) + (acc2 + acc3);
    }
}

// ---------------------------------------------------------------------------
// deconv2 stage B (per batch n): overlap-add gather.
// ---------------------------------------------------------------------------
__global__ __launch_bounds__(256) void k_dc2_scatter(const float* __restrict__ Dn,
                                                     const float* __restrict__ db,
                                                     float* __restrict__ outn) {
    int od = blockIdx.x;
    int pd = od & 3, qd = od >> 2;
    float bv = db[0];

    for (int p = threadIdx.x; p < 2270; p += 256) {
        int w = p % 10, oh = p / 10;
        int ph = oh & 3, qh = oh >> 2;
        float acc = 0.f;
#pragma unroll
        for (int s = 0; s < 3; s++) {
            int kpd = pd + 4 * s; int id = qd - s;
            if (kpd <= 10 && id >= 0 && id < 55) {
                int kd = 10 - kpd;
#pragma unroll
                for (int t = 0; t < 3; t++) {
                    int kph = ph + 4 * t; int ih = qh - t;
                    if (kph <= 10 && ih >= 0 && ih < 55) {
                        int kh = 10 - kph;
                        acc += Dn[(kd * 11 + kh) * 30250 + (id * 55 + ih) * 10 + w];
                    }
                }
            }
        }
        outn[(size_t)od * 2270 + p] = fmaxf(acc + bv, 0.f);
    }
}

// ---------------------------------------------------------------------------
extern "C" void kernel_launch(void* const* d_in, const int* in_sizes, int n_in,
                              void* d_out, int out_size, void* d_ws, size_t ws_size,
                              hipStream_t stream) {
    const float* x   = (const float*)d_in[0];
    const float* c1w = (const float*)d_in[1];
    const float* c1b = (const float*)d_in[2];
    const float* c2w = (const float*)d_in[3];
    const float* c2b = (const float*)d_in[4];
    const float* l1x = (const float*)d_in[5];
    const float* l1h = (const float*)d_in[6];
    const float* l1b = (const float*)d_in[7];
    const float* l2x = (const float*)d_in[8];
    const float* l2h = (const float*)d_in[9];
    const float* l2b = (const float*)d_in[10];
    const float* l3x = (const float*)d_in[11];
    const float* l3h = (const float*)d_in[12];
    const float* l3b = (const float*)d_in[13];
    const float* d1w = (const float*)d_in[14];
    const float* d1b = (const float*)d_in[15];
    const float* d2w = (const float*)d_in[16];
    const float* d2b = (const float*)d_in[17];

    float* ws = (float*)d_ws;
    float* A  = ws;
    float* B  = A + 30976000;
    float* C  = B + 3461120;
    float* S  = C + 3461120;
    float* Y1 = A + 20000000;
    float* Y2 = A + 24000000;
    float* Y3 = C;
    float* D  = B;
    int* FL = (int*)S;
    float* OUT = (float*)d_out;

    // encoder
    k_conv1<<<17600, 256, 0, stream>>>(x, c1w, c1b, A);
    k_conv2<<<4160, 128, 0, stream>>>(A, c2w, c2b, B);

    // ConvLSTM layer 1: 64 -> 64
    k_xconv<64, 256><<<208 * 26, 256, 0, stream>>>(B, l1x, l1b, A);
    k_rst<<<1, 256, 0, stream>>>(FL);
    k_lstm<64, 4><<<208, 1024, 0, stream>>>(A, l1h, Y1, FL);

    // ConvLSTM layer 2: 64 -> 32
    k_xconv<64, 128><<<208 * 26, 128, 0, stream>>>(Y1, l2x, l2b, A);
    k_rst<<<1, 256, 0, stream>>>(FL);
    k_lstm<32, 8><<<208, 1024, 0, stream>>>(A, l2h, Y2, FL);

    // ConvLSTM layer 3: 32 -> 64
    k_xconv<32, 256><<<208 * 26, 256, 0, stream>>>(Y2, l3x, l3b, A);
    k_rst<<<1, 256, 0, stream>>>(FL);
    k_lstm<64, 4><<<208, 1024, 0, stream>>>(A, l3h, Y3, FL);

    // decoder
    k_deconv1<<<8800, 256, 0, stream>>>(Y3, d1w, d1b, A);

    // deconv2: two-stage per batch
    for (int n = 0; n < 8; n++) {
        const float* d1n = A + (size_t)n * 3872000;
        float* outn = OUT + (size_t)n * 515290;
        k_dc2_gemm<<<dim3(119, 2), 256, 0, stream>>>(d1n, d2w, D);
        k_dc2_scatter<<<227, 256, 0, stream>>>(D, d2b, outn);
    }
}

// Round 13
// 3741.643 us; speedup vs baseline: 2.0698x; 2.0698x over previous
//
#include <hip/hip_runtime.h>
#include <math.h>

// ---------------------------------------------------------------------------
// SpatioTemporalAutoEncoder: conv3d x2 -> ConvLSTM2D x3 -> conv3d_transpose x2
// All fp32. Layouts are the reference's NDHWC flattened row-major.
// ---------------------------------------------------------------------------

__device__ __forceinline__ float hsig(float x) {
    float y = 0.2f * x + 0.5f;
    return fminf(fmaxf(y, 0.f), 1.f);
}

// ---------------------------------------------------------------------------
// conv1: x (8,227,227,10,1) * w (11,11,1,1,128) stride (4,4,1) + b, relu
//   -> e1 (8,55,55,10,128)
// ---------------------------------------------------------------------------
__global__ __launch_bounds__(256) void k_conv1(const float* __restrict__ x,
                                               const float* __restrict__ w1,
                                               const float* __restrict__ b1,
                                               float* __restrict__ e1) {
    int bid = blockIdx.x;
    int ht = bid & 3; int tmp = bid >> 2;
    int w = tmp % 10; tmp /= 10;
    int d = tmp % 55; int n = tmp / 55;
    int h0 = ht * 16;

    __shared__ __align__(16) float patch[11][72];
    int tid = threadIdx.x;
    for (int idx = tid; idx < 11 * 71; idx += 256) {
        int j = idx % 71; int kd = idx / 71;
        int rr = d * 4 + kd; int cc = h0 * 4 + j;
        float v = 0.f;
        if (cc < 227) v = x[((n * 227 + rr) * 227 + cc) * 10 + w];
        patch[kd][j] = v;
    }
    __syncthreads();

    int co = tid & 127, pg = tid >> 7;
    float acc[8];
#pragma unroll
    for (int p = 0; p < 8; p++) acc[p] = 0.f;

    for (int kd = 0; kd < 11; kd++) {
        const float4* row = (const float4*)&patch[kd][pg * 32];
        float rr2[40];
#pragma unroll
        for (int q = 0; q < 10; q++) {
            float4 t4 = row[q];
            rr2[4 * q] = t4.x; rr2[4 * q + 1] = t4.y; rr2[4 * q + 2] = t4.z; rr2[4 * q + 3] = t4.w;
        }
        const float* wp = w1 + (kd * 11) * 128 + co;
#pragma unroll
        for (int kh = 0; kh < 11; kh++) {
            float wv = wp[kh * 128];
#pragma unroll
            for (int p = 0; p < 8; p++) acc[p] += rr2[p * 4 + kh] * wv;
        }
    }
    float bv = b1[co];
#pragma unroll
    for (int p = 0; p < 8; p++) {
        int h = h0 + pg * 8 + p;
        if (h < 55)
            e1[(((n * 55 + d) * 55 + h) * 10 + w) * 128 + co] = fmaxf(acc[p] + bv, 0.f);
    }
}

// ---------------------------------------------------------------------------
// conv2: e1 (8,55,55,10,128) * w (5,5,1,128,64) stride (2,2,1) + b, relu
//   -> e2 (8,26,26,10,64)
// R11 inner structure (930us, VGPR=52, low bank conflict) + R12's proven
// XCD-chunked block remap: 2080 = 8 x 260, each XCD gets one full n so
// d-adjacent blocks (sharing 3/5 input rows) hit the same L2.
// R12 lesson: do NOT runtime-index register arrays (rule #20) and do NOT
// use pow-2 ci-stride LDS layouts (16-way write conflicts).
// ---------------------------------------------------------------------------
__global__ __launch_bounds__(128) void k_conv2(const float* __restrict__ e1,
                                               const float* __restrict__ w2,
                                               const float* __restrict__ b2,
                                               float* __restrict__ e2) {
    int bid = (blockIdx.x & 7) * 260 + (blockIdx.x >> 3);  // XCD chunking
    int w = bid % 10; int tmp = bid / 10;
    int d = tmp % 26; int n = tmp / 26;

    __shared__ __align__(16) float patch[5][16][60];
    int tid = threadIdx.x;
    int co = tid & 63, pg = tid >> 6;
    float bv = b2[co];
    float acc[14];
#pragma unroll
    for (int p = 0; p < 14; p++) acc[p] = bv;

    for (int c0 = 0; c0 < 128; c0 += 16) {
        __syncthreads();
        for (int idx = tid; idx < 5 * 59 * 16; idx += 128) {
            int ci = idx & 15; int t2 = idx >> 4;
            int col = t2 % 59; int kr = t2 / 59;
            float v = 0.f;
            if (col < 55)
                v = e1[(((n * 55 + d * 2 + kr) * 55 + col) * 10 + w) * 128 + c0 + ci];
            patch[kr][ci][col] = v;
        }
        __syncthreads();
        int base = pg * 28;
        for (int kr = 0; kr < 5; kr++) {
            for (int ci = 0; ci < 16; ci++) {
                const float4* row = (const float4*)&patch[kr][ci][base];
                float rr2[32];
#pragma unroll
                for (int u = 0; u < 8; u++) {
                    float4 t4 = row[u];
                    rr2[4 * u] = t4.x; rr2[4 * u + 1] = t4.y; rr2[4 * u + 2] = t4.z; rr2[4 * u + 3] = t4.w;
                }
                const float* wp = w2 + ((kr * 5) * 128 + c0 + ci) * 64 + co;
#pragma unroll
                for (int kh = 0; kh < 5; kh++) {
                    float wv = wp[kh * 128 * 64];
#pragma unroll
                    for (int p = 0; p < 14; p++) acc[p] += rr2[2 * p + kh] * wv;
                }
            }
        }
    }
#pragma unroll
    for (int p = 0; p < 14; p++) {
        int h = pg * 14 + p;
        if (h < 26)
            e2[(((n * 26 + d) * 26 + h) * 10 + w) * 64 + co] = fmaxf(acc[p], 0.f);
    }
}

// ---------------------------------------------------------------------------
// x-conv for ConvLSTM: 3x3 SAME conv over 26x10 frames, batched over 208
// frames. in: [fr = n*26+t][r][c][CIN]; out xz: [t*8+n][r][c][COUT] (+bias)
// ---------------------------------------------------------------------------
template <int CIN, int COUT>
__global__ __launch_bounds__(COUT) void k_xconv(const float* __restrict__ in,
                                                const float* __restrict__ wx,
                                                const float* __restrict__ bias,
                                                float* __restrict__ xz) {
    int bid = blockIdx.x;
    int r = bid % 26; int fr = bid / 26;
    int n = fr / 26, t = fr % 26;

    __shared__ __align__(16) float patch[3][CIN][12];
    int tid = threadIdx.x;
    const float* inf = in + (size_t)fr * (26 * 10 * CIN);
    for (int idx = tid; idx < 3 * 12 * CIN; idx += COUT) {
        int ci = idx % CIN; int t2 = idx / CIN;
        int col = t2 % 12; int kr = t2 / 12;
        int rr = r - 1 + kr; int cc = col - 1;
        float v = 0.f;
        if (rr >= 0 && rr < 26 && cc >= 0 && cc < 10)
            v = inf[(rr * 10 + cc) * CIN + ci];
        patch[kr][ci][col] = v;
    }
    __syncthreads();

    int co = tid;
    float bv = bias[co];
    float acc[10];
#pragma unroll
    for (int c = 0; c < 10; c++) acc[c] = bv;

    for (int kr = 0; kr < 3; kr++) {
        for (int ci0 = 0; ci0 < CIN; ci0 += 4) {
            float wv[4][3];
#pragma unroll
            for (int u = 0; u < 4; u++) {
                const float* wp = wx + ((kr * 3) * CIN + ci0 + u) * COUT + co;
#pragma unroll
                for (int kc = 0; kc < 3; kc++) wv[u][kc] = wp[kc * CIN * COUT];
            }
#pragma unroll
            for (int u = 0; u < 4; u++) {
                const float4* row = (const float4*)&patch[kr][ci0 + u][0];
                float rr2[12];
#pragma unroll
                for (int q = 0; q < 3; q++) {
                    float4 t4 = row[q];
                    rr2[4 * q] = t4.x; rr2[4 * q + 1] = t4.y;
                    rr2[4 * q + 2] = t4.z; rr2[4 * q + 3] = t4.w;
                }
#pragma unroll
                for (int kc = 0; kc < 3; kc++) {
                    float w_ = wv[u][kc];
#pragma unroll
                    for (int c = 0; c < 10; c++) acc[c] += rr2[c + kc] * w_;
                }
            }
        }
    }
    float* outp = xz + ((size_t)(t * 8 + n) * 260 + r * 10) * COUT + co;
#pragma unroll
    for (int c = 0; c < 10; c++) outp[c * COUT] = acc[c];
}

// ---------------------------------------------------------------------------
// Flag reset (before each LSTM layer): flags[b*26+r] = steps completed.
// ---------------------------------------------------------------------------
__global__ void k_rst(int* __restrict__ f) {
    if (threadIdx.x < 208)
        __hip_atomic_store(f + threadIdx.x, 0, __ATOMIC_RELAXED,
                           __HIP_MEMORY_SCOPE_AGENT);
}

// ---------------------------------------------------------------------------
// ConvLSTM layer, flag-skew pipeline, spill-free scheduling. (R11, passing.)
// RELEASE flag publish; agent-scope atomic halo/publish; dedicated y buffers;
// no per-thread array live across __syncthreads() (64-VGPR cap @1024 thr).
// ---------------------------------------------------------------------------
template <int F, int QS>
__global__ __launch_bounds__(4 * F * QS) void k_lstm(const float* __restrict__ xz,
                                                     const float* __restrict__ wh,
                                                     float* __restrict__ y,
                                                     int* __restrict__ flags) {
    constexpr int C4 = 4 * F;
    constexpr int NT = 4 * F * QS;
    constexpr int CQ = F / QS;
    int bid = blockIdx.x;
    int r = bid % 26; int b = bid / 26;
    int tid = threadIdx.x;
    int co = tid & (C4 - 1);
    int q = tid / C4;
    int ci0 = q * CQ;

    __shared__ __align__(16) float patch[3][F][12];
    __shared__ float zpart[QS][10][C4];

    for (int i = tid; i < 3 * F * 12; i += NT) ((float*)patch)[i] = 0.f;
    __syncthreads();

    float creg = 0.f;
    int gc = tid / F, gf = tid % F;
    int* fl = flags + b * 26;

    for (int t = 0; t < 26; t++) {
        if (t > 0) {
            if (tid < 2) {
                int nb = (tid == 0) ? r - 1 : r + 1;
                if (nb >= 0 && nb < 26) {
                    while (__hip_atomic_load(fl + nb, __ATOMIC_RELAXED,
                                             __HIP_MEMORY_SCOPE_AGENT) < t)
                        __builtin_amdgcn_s_sleep(1);
                }
            }
            __syncthreads();

            for (int i = tid; i < 2 * 10 * F; i += NT) {
                int ci = i % F; int t2 = i / F;
                int col = t2 % 10; int s = t2 / 10;
                int kr = 2 * s; int rr = r - 1 + kr;
                float v = 0.f;
                if (rr >= 0 && rr < 26)
                    v = __hip_atomic_load(
                        &y[((((size_t)b * 26 + (t - 1)) * 26 + rr) * 10 + col) * F + ci],
                        __ATOMIC_RELAXED, __HIP_MEMORY_SCOPE_AGENT);
                patch[kr][ci][col + 1] = v;
            }
            __syncthreads();
        }

        float acc[10];
        if (q == 0) {
            const float* xp = xz + ((size_t)(t * 8 + b) * 260 + r * 10) * C4 + co;
#pragma unroll
            for (int c = 0; c < 10; c++) acc[c] = xp[c * C4];
        } else {
#pragma unroll
            for (int c = 0; c < 10; c++) acc[c] = 0.f;
        }

        if (t > 0) {
            const int krseq[3] = {1, 0, 2};
            for (int kk = 0; kk < 3; kk++) {
                const int kr = krseq[kk];
                for (int cu = 0; cu < CQ; cu += 4) {
                    float wv[4][3];
#pragma unroll
                    for (int u = 0; u < 4; u++) {
                        const float* wp = wh + ((kr * 3) * F + ci0 + cu + u) * C4 + co;
#pragma unroll
                        for (int kc = 0; kc < 3; kc++) wv[u][kc] = wp[kc * F * C4];
                    }
#pragma unroll
                    for (int u = 0; u < 4; u++) {
                        const float4* row = (const float4*)&patch[kr][ci0 + cu + u][0];
                        float rr2[12];
#pragma unroll
                        for (int v4 = 0; v4 < 3; v4++) {
                            float4 t4 = row[v4];
                            rr2[4 * v4] = t4.x; rr2[4 * v4 + 1] = t4.y;
                            rr2[4 * v4 + 2] = t4.z; rr2[4 * v4 + 3] = t4.w;
                        }
#pragma unroll
                        for (int kc = 0; kc < 3; kc++) {
                            float w_ = wv[u][kc];
#pragma unroll
                            for (int c = 0; c < 10; c++) acc[c] += rr2[c + kc] * w_;
                        }
                    }
                }
            }
        }

#pragma unroll
        for (int c = 0; c < 10; c++) zpart[q][c][co] = acc[c];
        __syncthreads();

        if (tid < 10 * F) {
            float zi = 0.f, zf = 0.f, zg = 0.f, zo = 0.f;
#pragma unroll
            for (int qq = 0; qq < QS; qq++) {
                zi += zpart[qq][gc][gf];
                zf += zpart[qq][gc][F + gf];
                zg += zpart[qq][gc][2 * F + gf];
                zo += zpart[qq][gc][3 * F + gf];
            }
            float cn = hsig(zf) * creg + hsig(zi) * tanhf(zg);
            float hn = hsig(zo) * tanhf(cn);
            creg = cn;
            __hip_atomic_store(
                &y[((((size_t)b * 26 + t) * 26 + r) * 10 + gc) * F + gf], hn,
                __ATOMIC_RELAXED, __HIP_MEMORY_SCOPE_AGENT);
            patch[1][gf][gc + 1] = hn;
        }
        __syncthreads();

        if (tid == 0)
            __hip_atomic_store(fl + r, t + 1, __ATOMIC_RELEASE,
                               __HIP_MEMORY_SCOPE_AGENT);
    }
}

// ---------------------------------------------------------------------------
// deconv1: h3 (8,26,26,10,64) *T w (5,5,1,64,128) stride (2,2,1) + b, relu
//   -> d1 (8,55,55,10,128)
// ---------------------------------------------------------------------------
__global__ __launch_bounds__(256) void k_deconv1(const float* __restrict__ h3,
                                                 const float* __restrict__ dw,
                                                 const float* __restrict__ db,
                                                 float* __restrict__ out) {
    int bid = blockIdx.x;
    int ht = bid & 1; int tmp = bid >> 1;
    int w = tmp % 10; tmp /= 10;
    int od = tmp % 55; int n = tmp / 55;

    __shared__ __align__(16) float patch[3][64][24];
    int tid = threadIdx.x;
    int odd = od & 1;
    int id0 = odd ? (od - 3) / 2 : od / 2 - 2;
    int ihb = ht * 16 - 2;
    for (int idx = tid; idx < 3 * 20 * 64; idx += 256) {
        int ci = idx & 63; int t2 = idx >> 6;
        int j = t2 % 20; int s = t2 / 20;
        int id = id0 + s; int ih = ihb + j;
        float v = 0.f;
        if (id >= 0 && id < 26 && ih >= 0 && ih < 26)
            v = h3[((((size_t)n * 26 + id) * 26 + ih) * 10 + w) * 64 + ci];
        patch[s][ci][j] = v;
    }
    __syncthreads();

    int co = tid & 127, pg = tid >> 7;
    float acc[16];
#pragma unroll
    for (int p = 0; p < 16; p++) acc[p] = 0.f;

    int nslot = odd ? 2 : 3;
    for (int s = 0; s < nslot; s++) {
        int kd = odd ? (1 + 2 * s) : 2 * s;
        for (int ci = 0; ci < 64; ci++) {
            const float* pr = &patch[s][ci][pg * 8];
            float rr2[10];
            {
                float4 t0 = *(const float4*)pr;
                float4 t1 = *(const float4*)(pr + 4);
                float2 t2v = *(const float2*)(pr + 8);
                rr2[0] = t0.x; rr2[1] = t0.y; rr2[2] = t0.z; rr2[3] = t0.w;
                rr2[4] = t1.x; rr2[5] = t1.y; rr2[6] = t1.z; rr2[7] = t1.w;
                rr2[8] = t2v.x; rr2[9] = t2v.y;
            }
            const float* wp = dw + ((kd * 5) * 64 + ci) * 128 + co;
#pragma unroll
            for (int kh = 0; kh < 5; kh++) {
                float wv = wp[kh * 64 * 128];
                const int po = kh & 1;
                const int rbase = (kh + po) >> 1;
#pragma unroll
                for (int jj = 0; jj < 8; jj++)
                    acc[po + 2 * jj] += rr2[rbase + jj] * wv;
            }
        }
    }
    float bv = db[co];
#pragma unroll
    for (int p = 0; p < 16; p++) {
        int oh = ht * 32 + pg * 16 + p;
        if (oh < 55)
            out[((((size_t)n * 55 + od) * 55 + oh) * 10 + w) * 128 + co] =
                fmaxf(acc[p] + bv, 0.f);
    }
}

// ---------------------------------------------------------------------------
// deconv2 stage A (per batch n): D[k][pix] = dot(d1n[pix][0:128], dw[k][0:128])
// ---------------------------------------------------------------------------
__global__ __launch_bounds__(256) void k_dc2_gemm(const float* __restrict__ d1n,
                                                  const float* __restrict__ dw,
                                                  float* __restrict__ Dn) {
    int pix = blockIdx.x * 256 + threadIdx.x;
    bool act = pix < 30250;
    int khalf = blockIdx.y;

    float a[128];
    const float* ap = d1n + (size_t)(act ? pix : 0) * 128;
#pragma unroll
    for (int i = 0; i < 32; i++) {
        float4 v = ((const float4*)ap)[i];
        a[4 * i] = v.x; a[4 * i + 1] = v.y; a[4 * i + 2] = v.z; a[4 * i + 3] = v.w;
    }

    int k0 = khalf * 61;
    int kn = 61 - khalf;
    for (int kk = 0; kk < kn; kk++) {
        int k = k0 + kk;
        const float* wp = dw + k * 128;
        float acc0 = 0.f, acc1 = 0.f, acc2 = 0.f, acc3 = 0.f;
#pragma unroll
        for (int i = 0; i < 32; i++) {
            acc0 += a[4 * i + 0] * wp[4 * i + 0];
            acc1 += a[4 * i + 1] * wp[4 * i + 1];
            acc2 += a[4 * i + 2] * wp[4 * i + 2];
            acc3 += a[4 * i + 3] * wp[4 * i + 3];
        }
        if (act) Dn[k * 30250 + pix] = (acc0 + acc1) + (acc2 + acc3);
    }
}

// ---------------------------------------------------------------------------
// deconv2 stage B (per batch n): overlap-add gather.
// ---------------------------------------------------------------------------
__global__ __launch_bounds__(256) void k_dc2_scatter(const float* __restrict__ Dn,
                                                     const float* __restrict__ db,
                                                     float* __restrict__ outn) {
    int od = blockIdx.x;
    int pd = od & 3, qd = od >> 2;
    float bv = db[0];

    for (int p = threadIdx.x; p < 2270; p += 256) {
        int w = p % 10, oh = p / 10;
        int ph = oh & 3, qh = oh >> 2;
        float acc = 0.f;
#pragma unroll
        for (int s = 0; s < 3; s++) {
            int kpd = pd + 4 * s; int id = qd - s;
            if (kpd <= 10 && id >= 0 && id < 55) {
                int kd = 10 - kpd;
#pragma unroll
                for (int t = 0; t < 3; t++) {
                    int kph = ph + 4 * t; int ih = qh - t;
                    if (kph <= 10 && ih >= 0 && ih < 55) {
                        int kh = 10 - kph;
                        acc += Dn[(kd * 11 + kh) * 30250 + (id * 55 + ih) * 10 + w];
                    }
                }
            }
        }
        outn[(size_t)od * 2270 + p] = fmaxf(acc + bv, 0.f);
    }
}

// ---------------------------------------------------------------------------
extern "C" void kernel_launch(void* const* d_in, const int* in_sizes, int n_in,
                              void* d_out, int out_size, void* d_ws, size_t ws_size,
                              hipStream_t stream) {
    const float* x   = (const float*)d_in[0];
    const float* c1w = (const float*)d_in[1];
    const float* c1b = (const float*)d_in[2];
    const float* c2w = (const float*)d_in[3];
    const float* c2b = (const float*)d_in[4];
    const float* l1x = (const float*)d_in[5];
    const float* l1h = (const float*)d_in[6];
    const float* l1b = (const float*)d_in[7];
    const float* l2x = (const float*)d_in[8];
    const float* l2h = (const float*)d_in[9];
    const float* l2b = (const float*)d_in[10];
    const float* l3x = (const float*)d_in[11];
    const float* l3h = (const float*)d_in[12];
    const float* l3b = (const float*)d_in[13];
    const float* d1w = (const float*)d_in[14];
    const float* d1b = (const float*)d_in[15];
    const float* d2w = (const float*)d_in[16];
    const float* d2b = (const float*)d_in[17];

    float* ws = (float*)d_ws;
    float* A  = ws;
    float* B  = A + 30976000;
    float* C  = B + 3461120;
    float* S  = C + 3461120;
    float* Y1 = A + 20000000;
    float* Y2 = A + 24000000;
    float* Y3 = C;
    float* D  = B;
    int* FL = (int*)S;
    float* OUT = (float*)d_out;

    // encoder
    k_conv1<<<17600, 256, 0, stream>>>(x, c1w, c1b, A);
    k_conv2<<<2080, 128, 0, stream>>>(A, c2w, c2b, B);

    // ConvLSTM layer 1: 64 -> 64
    k_xconv<64, 256><<<208 * 26, 256, 0, stream>>>(B, l1x, l1b, A);
    k_rst<<<1, 256, 0, stream>>>(FL);
    k_lstm<64, 4><<<208, 1024, 0, stream>>>(A, l1h, Y1, FL);

    // ConvLSTM layer 2: 64 -> 32
    k_xconv<64, 128><<<208 * 26, 128, 0, stream>>>(Y1, l2x, l2b, A);
    k_rst<<<1, 256, 0, stream>>>(FL);
    k_lstm<32, 8><<<208, 1024, 0, stream>>>(A, l2h, Y2, FL);

    // ConvLSTM layer 3: 32 -> 64
    k_xconv<32, 256><<<208 * 26, 256, 0, stream>>>(Y2, l3x, l3b, A);
    k_rst<<<1, 256, 0, stream>>>(FL);
    k_lstm<64, 4><<<208, 1024, 0, stream>>>(A, l3h, Y3, FL);

    // decoder
    k_deconv1<<<8800, 256, 0, stream>>>(Y3, d1w, d1b, A);

    // deconv2: two-stage per batch
    for (int n = 0; n < 8; n++) {
        const float* d1n = A + (size_t)n * 3872000;
        float* outn = OUT + (size_t)n * 515290;
        k_dc2_gemm<<<dim3(119, 2), 256, 0, stream>>>(d1n, d2w, D);
        k_dc2_scatter<<<227, 256, 0, stream>>>(D, d2b, outn);
    }
}

// Round 14
// 3352.445 us; speedup vs baseline: 2.3100x; 1.1161x over previous
//
#include <hip/hip_runtime.h>
#include <math.h>

// ---------------------------------------------------------------------------
// SpatioTemporalAutoEncoder: conv3d x2 -> ConvLSTM2D x3 -> conv3d_transpose x2
// All fp32. Layouts are the reference's NDHWC flattened row-major.
// ---------------------------------------------------------------------------

__device__ __forceinline__ float hsig(float x) {
    float y = 0.2f * x + 0.5f;
    return fminf(fmaxf(y, 0.f), 1.f);
}

// ---------------------------------------------------------------------------
// conv1: x (8,227,227,10,1) * w (11,11,1,1,128) stride (4,4,1) + b, relu
//   -> e1 (8,55,55,10,128)
// ---------------------------------------------------------------------------
__global__ __launch_bounds__(256) void k_conv1(const float* __restrict__ x,
                                               const float* __restrict__ w1,
                                               const float* __restrict__ b1,
                                               float* __restrict__ e1) {
    int bid = blockIdx.x;
    int ht = bid & 3; int tmp = bid >> 2;
    int w = tmp % 10; tmp /= 10;
    int d = tmp % 55; int n = tmp / 55;
    int h0 = ht * 16;

    __shared__ __align__(16) float patch[11][72];
    int tid = threadIdx.x;
    for (int idx = tid; idx < 11 * 71; idx += 256) {
        int j = idx % 71; int kd = idx / 71;
        int rr = d * 4 + kd; int cc = h0 * 4 + j;
        float v = 0.f;
        if (cc < 227) v = x[((n * 227 + rr) * 227 + cc) * 10 + w];
        patch[kd][j] = v;
    }
    __syncthreads();

    int co = tid & 127, pg = tid >> 7;
    float acc[8];
#pragma unroll
    for (int p = 0; p < 8; p++) acc[p] = 0.f;

    for (int kd = 0; kd < 11; kd++) {
        const float4* row = (const float4*)&patch[kd][pg * 32];
        float rr2[40];
#pragma unroll
        for (int q = 0; q < 10; q++) {
            float4 t4 = row[q];
            rr2[4 * q] = t4.x; rr2[4 * q + 1] = t4.y; rr2[4 * q + 2] = t4.z; rr2[4 * q + 3] = t4.w;
        }
        const float* wp = w1 + (kd * 11) * 128 + co;
#pragma unroll
        for (int kh = 0; kh < 11; kh++) {
            float wv = wp[kh * 128];
#pragma unroll
            for (int p = 0; p < 8; p++) acc[p] += rr2[p * 4 + kh] * wv;
        }
    }
    float bv = b1[co];
#pragma unroll
    for (int p = 0; p < 8; p++) {
        int h = h0 + pg * 8 + p;
        if (h < 55)
            e1[(((n * 55 + d) * 55 + h) * 10 + w) * 128 + co] = fmaxf(acc[p] + bv, 0.f);
    }
}

// ---------------------------------------------------------------------------
// conv2: e1 (8,55,55,10,128) * w (5,5,1,128,64) stride (2,2,1) + b, relu
//   -> e2 (8,26,26,10,64)
// R13 structure + XCD chunking + ci-unroll-4 weight hoisting (20 outstanding
// L2 loads instead of 5). Per-acc accumulation order is IDENTICAL to R13
// (ci ascending, kh inner) -> bit-identical output.
// ---------------------------------------------------------------------------
__global__ __launch_bounds__(128) void k_conv2(const float* __restrict__ e1,
                                               const float* __restrict__ w2,
                                               const float* __restrict__ b2,
                                               float* __restrict__ e2) {
    int bid = (blockIdx.x & 7) * 260 + (blockIdx.x >> 3);  // XCD chunking
    int w = bid % 10; int tmp = bid / 10;
    int d = tmp % 26; int n = tmp / 26;

    __shared__ __align__(16) float patch[5][16][60];
    int tid = threadIdx.x;
    int co = tid & 63, pg = tid >> 6;
    float bv = b2[co];
    float acc[14];
#pragma unroll
    for (int p = 0; p < 14; p++) acc[p] = bv;

    for (int c0 = 0; c0 < 128; c0 += 16) {
        __syncthreads();
        for (int idx = tid; idx < 5 * 59 * 16; idx += 128) {
            int ci = idx & 15; int t2 = idx >> 4;
            int col = t2 % 59; int kr = t2 / 59;
            float v = 0.f;
            if (col < 55)
                v = e1[(((n * 55 + d * 2 + kr) * 55 + col) * 10 + w) * 128 + c0 + ci];
            patch[kr][ci][col] = v;
        }
        __syncthreads();
        int base = pg * 28;
        for (int kr = 0; kr < 5; kr++) {
            for (int ci0 = 0; ci0 < 16; ci0 += 4) {
                float wv[4][5];
#pragma unroll
                for (int u = 0; u < 4; u++) {
                    const float* wp = w2 + ((kr * 5) * 128 + c0 + ci0 + u) * 64 + co;
#pragma unroll
                    for (int kh = 0; kh < 5; kh++) wv[u][kh] = wp[kh * 128 * 64];
                }
#pragma unroll
                for (int u = 0; u < 4; u++) {
                    const float4* row = (const float4*)&patch[kr][ci0 + u][base];
                    float rr2[32];
#pragma unroll
                    for (int q = 0; q < 8; q++) {
                        float4 t4 = row[q];
                        rr2[4 * q] = t4.x; rr2[4 * q + 1] = t4.y;
                        rr2[4 * q + 2] = t4.z; rr2[4 * q + 3] = t4.w;
                    }
#pragma unroll
                    for (int kh = 0; kh < 5; kh++) {
                        float w_ = wv[u][kh];
#pragma unroll
                        for (int p = 0; p < 14; p++) acc[p] += rr2[2 * p + kh] * w_;
                    }
                }
            }
        }
    }
#pragma unroll
    for (int p = 0; p < 14; p++) {
        int h = pg * 14 + p;
        if (h < 26)
            e2[(((n * 26 + d) * 26 + h) * 10 + w) * 64 + co] = fmaxf(acc[p], 0.f);
    }
}

// ---------------------------------------------------------------------------
// x-conv for ConvLSTM: 3x3 SAME conv over 26x10 frames, batched over 208
// frames. in: [fr = n*26+t][r][c][CIN]; out xz: [t*8+n][r][c][COUT] (+bias)
// ---------------------------------------------------------------------------
template <int CIN, int COUT>
__global__ __launch_bounds__(COUT) void k_xconv(const float* __restrict__ in,
                                                const float* __restrict__ wx,
                                                const float* __restrict__ bias,
                                                float* __restrict__ xz) {
    int bid = blockIdx.x;
    int r = bid % 26; int fr = bid / 26;
    int n = fr / 26, t = fr % 26;

    __shared__ __align__(16) float patch[3][CIN][12];
    int tid = threadIdx.x;
    const float* inf = in + (size_t)fr * (26 * 10 * CIN);
    for (int idx = tid; idx < 3 * 12 * CIN; idx += COUT) {
        int ci = idx % CIN; int t2 = idx / CIN;
        int col = t2 % 12; int kr = t2 / 12;
        int rr = r - 1 + kr; int cc = col - 1;
        float v = 0.f;
        if (rr >= 0 && rr < 26 && cc >= 0 && cc < 10)
            v = inf[(rr * 10 + cc) * CIN + ci];
        patch[kr][ci][col] = v;
    }
    __syncthreads();

    int co = tid;
    float bv = bias[co];
    float acc[10];
#pragma unroll
    for (int c = 0; c < 10; c++) acc[c] = bv;

    for (int kr = 0; kr < 3; kr++) {
        for (int ci0 = 0; ci0 < CIN; ci0 += 4) {
            float wv[4][3];
#pragma unroll
            for (int u = 0; u < 4; u++) {
                const float* wp = wx + ((kr * 3) * CIN + ci0 + u) * COUT + co;
#pragma unroll
                for (int kc = 0; kc < 3; kc++) wv[u][kc] = wp[kc * CIN * COUT];
            }
#pragma unroll
            for (int u = 0; u < 4; u++) {
                const float4* row = (const float4*)&patch[kr][ci0 + u][0];
                float rr2[12];
#pragma unroll
                for (int q = 0; q < 3; q++) {
                    float4 t4 = row[q];
                    rr2[4 * q] = t4.x; rr2[4 * q + 1] = t4.y;
                    rr2[4 * q + 2] = t4.z; rr2[4 * q + 3] = t4.w;
                }
#pragma unroll
                for (int kc = 0; kc < 3; kc++) {
                    float w_ = wv[u][kc];
#pragma unroll
                    for (int c = 0; c < 10; c++) acc[c] += rr2[c + kc] * w_;
                }
            }
        }
    }
    float* outp = xz + ((size_t)(t * 8 + n) * 260 + r * 10) * COUT + co;
#pragma unroll
    for (int c = 0; c < 10; c++) outp[c * COUT] = acc[c];
}

// ---------------------------------------------------------------------------
// Flag reset (before each LSTM layer): flags[b*26+r] = steps completed.
// ---------------------------------------------------------------------------
__global__ void k_rst(int* __restrict__ f) {
    if (threadIdx.x < 208)
        __hip_atomic_store(f + threadIdx.x, 0, __ATOMIC_RELAXED,
                           __HIP_MEMORY_SCOPE_AGENT);
}

// ---------------------------------------------------------------------------
// ConvLSTM layer, flag-skew pipeline, spill-free scheduling. (R11, passing.)
// RELEASE flag publish; agent-scope atomic halo/publish; dedicated y buffers;
// no per-thread array live across __syncthreads() (64-VGPR cap @1024 thr).
// ---------------------------------------------------------------------------
template <int F, int QS>
__global__ __launch_bounds__(4 * F * QS) void k_lstm(const float* __restrict__ xz,
                                                     const float* __restrict__ wh,
                                                     float* __restrict__ y,
                                                     int* __restrict__ flags) {
    constexpr int C4 = 4 * F;
    constexpr int NT = 4 * F * QS;
    constexpr int CQ = F / QS;
    int bid = blockIdx.x;
    int r = bid % 26; int b = bid / 26;
    int tid = threadIdx.x;
    int co = tid & (C4 - 1);
    int q = tid / C4;
    int ci0 = q * CQ;

    __shared__ __align__(16) float patch[3][F][12];
    __shared__ float zpart[QS][10][C4];

    for (int i = tid; i < 3 * F * 12; i += NT) ((float*)patch)[i] = 0.f;
    __syncthreads();

    float creg = 0.f;
    int gc = tid / F, gf = tid % F;
    int* fl = flags + b * 26;

    for (int t = 0; t < 26; t++) {
        if (t > 0) {
            if (tid < 2) {
                int nb = (tid == 0) ? r - 1 : r + 1;
                if (nb >= 0 && nb < 26) {
                    while (__hip_atomic_load(fl + nb, __ATOMIC_RELAXED,
                                             __HIP_MEMORY_SCOPE_AGENT) < t)
                        __builtin_amdgcn_s_sleep(1);
                }
            }
            __syncthreads();

            for (int i = tid; i < 2 * 10 * F; i += NT) {
                int ci = i % F; int t2 = i / F;
                int col = t2 % 10; int s = t2 / 10;
                int kr = 2 * s; int rr = r - 1 + kr;
                float v = 0.f;
                if (rr >= 0 && rr < 26)
                    v = __hip_atomic_load(
                        &y[((((size_t)b * 26 + (t - 1)) * 26 + rr) * 10 + col) * F + ci],
                        __ATOMIC_RELAXED, __HIP_MEMORY_SCOPE_AGENT);
                patch[kr][ci][col + 1] = v;
            }
            __syncthreads();
        }

        float acc[10];
        if (q == 0) {
            const float* xp = xz + ((size_t)(t * 8 + b) * 260 + r * 10) * C4 + co;
#pragma unroll
            for (int c = 0; c < 10; c++) acc[c] = xp[c * C4];
        } else {
#pragma unroll
            for (int c = 0; c < 10; c++) acc[c] = 0.f;
        }

        if (t > 0) {
            const int krseq[3] = {1, 0, 2};
            for (int kk = 0; kk < 3; kk++) {
                const int kr = krseq[kk];
                for (int cu = 0; cu < CQ; cu += 4) {
                    float wv[4][3];
#pragma unroll
                    for (int u = 0; u < 4; u++) {
                        const float* wp = wh + ((kr * 3) * F + ci0 + cu + u) * C4 + co;
#pragma unroll
                        for (int kc = 0; kc < 3; kc++) wv[u][kc] = wp[kc * F * C4];
                    }
#pragma unroll
                    for (int u = 0; u < 4; u++) {
                        const float4* row = (const float4*)&patch[kr][ci0 + cu + u][0];
                        float rr2[12];
#pragma unroll
                        for (int v4 = 0; v4 < 3; v4++) {
                            float4 t4 = row[v4];
                            rr2[4 * v4] = t4.x; rr2[4 * v4 + 1] = t4.y;
                            rr2[4 * v4 + 2] = t4.z; rr2[4 * v4 + 3] = t4.w;
                        }
#pragma unroll
                        for (int kc = 0; kc < 3; kc++) {
                            float w_ = wv[u][kc];
#pragma unroll
                            for (int c = 0; c < 10; c++) acc[c] += rr2[c + kc] * w_;
                        }
                    }
                }
            }
        }

#pragma unroll
        for (int c = 0; c < 10; c++) zpart[q][c][co] = acc[c];
        __syncthreads();

        if (tid < 10 * F) {
            float zi = 0.f, zf = 0.f, zg = 0.f, zo = 0.f;
#pragma unroll
            for (int qq = 0; qq < QS; qq++) {
                zi += zpart[qq][gc][gf];
                zf += zpart[qq][gc][F + gf];
                zg += zpart[qq][gc][2 * F + gf];
                zo += zpart[qq][gc][3 * F + gf];
            }
            float cn = hsig(zf) * creg + hsig(zi) * tanhf(zg);
            float hn = hsig(zo) * tanhf(cn);
            creg = cn;
            __hip_atomic_store(
                &y[((((size_t)b * 26 + t) * 26 + r) * 10 + gc) * F + gf], hn,
                __ATOMIC_RELAXED, __HIP_MEMORY_SCOPE_AGENT);
            patch[1][gf][gc + 1] = hn;
        }
        __syncthreads();

        if (tid == 0)
            __hip_atomic_store(fl + r, t + 1, __ATOMIC_RELEASE,
                               __HIP_MEMORY_SCOPE_AGENT);
    }
}

// ---------------------------------------------------------------------------
// deconv1: h3 (8,26,26,10,64) *T w (5,5,1,64,128) stride (2,2,1) + b, relu
//   -> d1 (8,55,55,10,128)
// ---------------------------------------------------------------------------
__global__ __launch_bounds__(256) void k_deconv1(const float* __restrict__ h3,
                                                 const float* __restrict__ dw,
                                                 const float* __restrict__ db,
                                                 float* __restrict__ out) {
    int bid = blockIdx.x;
    int ht = bid & 1; int tmp = bid >> 1;
    int w = tmp % 10; tmp /= 10;
    int od = tmp % 55; int n = tmp / 55;

    __shared__ __align__(16) float patch[3][64][24];
    int tid = threadIdx.x;
    int odd = od & 1;
    int id0 = odd ? (od - 3) / 2 : od / 2 - 2;
    int ihb = ht * 16 - 2;
    for (int idx = tid; idx < 3 * 20 * 64; idx += 256) {
        int ci = idx & 63; int t2 = idx >> 6;
        int j = t2 % 20; int s = t2 / 20;
        int id = id0 + s; int ih = ihb + j;
        float v = 0.f;
        if (id >= 0 && id < 26 && ih >= 0 && ih < 26)
            v = h3[((((size_t)n * 26 + id) * 26 + ih) * 10 + w) * 64 + ci];
        patch[s][ci][j] = v;
    }
    __syncthreads();

    int co = tid & 127, pg = tid >> 7;
    float acc[16];
#pragma unroll
    for (int p = 0; p < 16; p++) acc[p] = 0.f;

    int nslot = odd ? 2 : 3;
    for (int s = 0; s < nslot; s++) {
        int kd = odd ? (1 + 2 * s) : 2 * s;
        for (int ci = 0; ci < 64; ci++) {
            const float* pr = &patch[s][ci][pg * 8];
            float rr2[10];
            {
                float4 t0 = *(const float4*)pr;
                float4 t1 = *(const float4*)(pr + 4);
                float2 t2v = *(const float2*)(pr + 8);
                rr2[0] = t0.x; rr2[1] = t0.y; rr2[2] = t0.z; rr2[3] = t0.w;
                rr2[4] = t1.x; rr2[5] = t1.y; rr2[6] = t1.z; rr2[7] = t1.w;
                rr2[8] = t2v.x; rr2[9] = t2v.y;
            }
            const float* wp = dw + ((kd * 5) * 64 + ci) * 128 + co;
#pragma unroll
            for (int kh = 0; kh < 5; kh++) {
                float wv = wp[kh * 64 * 128];
                const int po = kh & 1;
                const int rbase = (kh + po) >> 1;
#pragma unroll
                for (int jj = 0; jj < 8; jj++)
                    acc[po + 2 * jj] += rr2[rbase + jj] * wv;
            }
        }
    }
    float bv = db[co];
#pragma unroll
    for (int p = 0; p < 16; p++) {
        int oh = ht * 32 + pg * 16 + p;
        if (oh < 55)
            out[((((size_t)n * 55 + od) * 55 + oh) * 10 + w) * 128 + co] =
                fmaxf(acc[p] + bv, 0.f);
    }
}

// ---------------------------------------------------------------------------
// deconv2 stage A (per batch n): D[k][pix] = dot(d1n[pix][0:128], dw[k][0:128])
// Grid (119, 8): k split 16 + 7x15 -> 952 blocks (was 238; latency-bound).
// Each D value computed with the identical 4-way dot split -> bit-identical.
// ---------------------------------------------------------------------------
__global__ __launch_bounds__(256) void k_dc2_gemm(const float* __restrict__ d1n,
                                                  const float* __restrict__ dw,
                                                  float* __restrict__ Dn) {
    int pix = blockIdx.x * 256 + threadIdx.x;
    bool act = pix < 30250;
    int y = blockIdx.y;
    int k0 = (y == 0) ? 0 : 16 + (y - 1) * 15;
    int kn = (y == 0) ? 16 : 15;

    float a[128];
    const float* ap = d1n + (size_t)(act ? pix : 0) * 128;
#pragma unroll
    for (int i = 0; i < 32; i++) {
        float4 v = ((const float4*)ap)[i];
        a[4 * i] = v.x; a[4 * i + 1] = v.y; a[4 * i + 2] = v.z; a[4 * i + 3] = v.w;
    }

    for (int kk = 0; kk < kn; kk++) {
        int k = k0 + kk;
        const float* wp = dw + k * 128;
        float acc0 = 0.f, acc1 = 0.f, acc2 = 0.f, acc3 = 0.f;
#pragma unroll
        for (int i = 0; i < 32; i++) {
            acc0 += a[4 * i + 0] * wp[4 * i + 0];
            acc1 += a[4 * i + 1] * wp[4 * i + 1];
            acc2 += a[4 * i + 2] * wp[4 * i + 2];
            acc3 += a[4 * i + 3] * wp[4 * i + 3];
        }
        if (act) Dn[k * 30250 + pix] = (acc0 + acc1) + (acc2 + acc3);
    }
}

// ---------------------------------------------------------------------------
// deconv2 stage B (per batch n): overlap-add gather. Grid (227, 3): each
// block covers a 768-pixel slice of the 2270 (oh,w) pairs -> 681 blocks.
// Per-output computation identical -> bit-identical.
// ---------------------------------------------------------------------------
__global__ __launch_bounds__(256) void k_dc2_scatter(const float* __restrict__ Dn,
                                                     const float* __restrict__ db,
                                                     float* __restrict__ outn) {
    int od = blockIdx.x;
    int pd = od & 3, qd = od >> 2;
    float bv = db[0];
    int p0 = blockIdx.y * 768;
    int p1 = min(2270, p0 + 768);

    for (int p = p0 + threadIdx.x; p < p1; p += 256) {
        int w = p % 10, oh = p / 10;
        int ph = oh & 3, qh = oh >> 2;
        float acc = 0.f;
#pragma unroll
        for (int s = 0; s < 3; s++) {
            int kpd = pd + 4 * s; int id = qd - s;
            if (kpd <= 10 && id >= 0 && id < 55) {
                int kd = 10 - kpd;
#pragma unroll
                for (int t = 0; t < 3; t++) {
                    int kph = ph + 4 * t; int ih = qh - t;
                    if (kph <= 10 && ih >= 0 && ih < 55) {
                        int kh = 10 - kph;
                        acc += Dn[(kd * 11 + kh) * 30250 + (id * 55 + ih) * 10 + w];
                    }
                }
            }
        }
        outn[(size_t)od * 2270 + p] = fmaxf(acc + bv, 0.f);
    }
}

// ---------------------------------------------------------------------------
extern "C" void kernel_launch(void* const* d_in, const int* in_sizes, int n_in,
                              void* d_out, int out_size, void* d_ws, size_t ws_size,
                              hipStream_t stream) {
    const float* x   = (const float*)d_in[0];
    const float* c1w = (const float*)d_in[1];
    const float* c1b = (const float*)d_in[2];
    const float* c2w = (const float*)d_in[3];
    const float* c2b = (const float*)d_in[4];
    const float* l1x = (const float*)d_in[5];
    const float* l1h = (const float*)d_in[6];
    const float* l1b = (const float*)d_in[7];
    const float* l2x = (const float*)d_in[8];
    const float* l2h = (const float*)d_in[9];
    const float* l2b = (const float*)d_in[10];
    const float* l3x = (const float*)d_in[11];
    const float* l3h = (const float*)d_in[12];
    const float* l3b = (const float*)d_in[13];
    const float* d1w = (const float*)d_in[14];
    const float* d1b = (const float*)d_in[15];
    const float* d2w = (const float*)d_in[16];
    const float* d2b = (const float*)d_in[17];

    float* ws = (float*)d_ws;
    float* A  = ws;
    float* B  = A + 30976000;
    float* C  = B + 3461120;
    float* S  = C + 3461120;
    float* Y1 = A + 20000000;
    float* Y2 = A + 24000000;
    float* Y3 = C;
    float* D  = B;
    int* FL = (int*)S;
    float* OUT = (float*)d_out;

    // encoder
    k_conv1<<<17600, 256, 0, stream>>>(x, c1w, c1b, A);
    k_conv2<<<2080, 128, 0, stream>>>(A, c2w, c2b, B);

    // ConvLSTM layer 1: 64 -> 64
    k_xconv<64, 256><<<208 * 26, 256, 0, stream>>>(B, l1x, l1b, A);
    k_rst<<<1, 256, 0, stream>>>(FL);
    k_lstm<64, 4><<<208, 1024, 0, stream>>>(A, l1h, Y1, FL);

    // ConvLSTM layer 2: 64 -> 32
    k_xconv<64, 128><<<208 * 26, 128, 0, stream>>>(Y1, l2x, l2b, A);
    k_rst<<<1, 256, 0, stream>>>(FL);
    k_lstm<32, 8><<<208, 1024, 0, stream>>>(A, l2h, Y2, FL);

    // ConvLSTM layer 3: 32 -> 64
    k_xconv<32, 256><<<208 * 26, 256, 0, stream>>>(Y2, l3x, l3b, A);
    k_rst<<<1, 256, 0, stream>>>(FL);
    k_lstm<64, 4><<<208, 1024, 0, stream>>>(A, l3h, Y3, FL);

    // decoder
    k_deconv1<<<8800, 256, 0, stream>>>(Y3, d1w, d1b, A);

    // deconv2: two-stage per batch
    for (int n = 0; n < 8; n++) {
        const float* d1n = A + (size_t)n * 3872000;
        float* outn = OUT + (size_t)n * 515290;
        k_dc2_gemm<<<dim3(119, 8), 256, 0, stream>>>(d1n, d2w, D);
        k_dc2_scatter<<<dim3(227, 3), 256, 0, stream>>>(D, d2b, outn);
    }
}

// Round 15
// 3276.312 us; speedup vs baseline: 2.3637x; 1.0232x over previous
//
#include <hip/hip_runtime.h>
#include <math.h>

// ---------------------------------------------------------------------------
// SpatioTemporalAutoEncoder: conv3d x2 -> ConvLSTM2D x3 -> conv3d_transpose x2
// All fp32. Layouts are the reference's NDHWC flattened row-major.
// ---------------------------------------------------------------------------

__device__ __forceinline__ float hsig(float x) {
    float y = 0.2f * x + 0.5f;
    return fminf(fmaxf(y, 0.f), 1.f);
}

// ---------------------------------------------------------------------------
// conv1: x (8,227,227,10,1) * w (11,11,1,1,128) stride (4,4,1) + b, relu
//   -> e1 (8,55,55,10,128)
// ---------------------------------------------------------------------------
__global__ __launch_bounds__(256) void k_conv1(const float* __restrict__ x,
                                               const float* __restrict__ w1,
                                               const float* __restrict__ b1,
                                               float* __restrict__ e1) {
    int bid = blockIdx.x;
    int ht = bid & 3; int tmp = bid >> 2;
    int w = tmp % 10; tmp /= 10;
    int d = tmp % 55; int n = tmp / 55;
    int h0 = ht * 16;

    __shared__ __align__(16) float patch[11][72];
    int tid = threadIdx.x;
    for (int idx = tid; idx < 11 * 71; idx += 256) {
        int j = idx % 71; int kd = idx / 71;
        int rr = d * 4 + kd; int cc = h0 * 4 + j;
        float v = 0.f;
        if (cc < 227) v = x[((n * 227 + rr) * 227 + cc) * 10 + w];
        patch[kd][j] = v;
    }
    __syncthreads();

    int co = tid & 127, pg = tid >> 7;
    float acc[8];
#pragma unroll
    for (int p = 0; p < 8; p++) acc[p] = 0.f;

    for (int kd = 0; kd < 11; kd++) {
        const float4* row = (const float4*)&patch[kd][pg * 32];
        float rr2[40];
#pragma unroll
        for (int q = 0; q < 10; q++) {
            float4 t4 = row[q];
            rr2[4 * q] = t4.x; rr2[4 * q + 1] = t4.y; rr2[4 * q + 2] = t4.z; rr2[4 * q + 3] = t4.w;
        }
        const float* wp = w1 + (kd * 11) * 128 + co;
#pragma unroll
        for (int kh = 0; kh < 11; kh++) {
            float wv = wp[kh * 128];
#pragma unroll
            for (int p = 0; p < 8; p++) acc[p] += rr2[p * 4 + kh] * wv;
        }
    }
    float bv = b1[co];
#pragma unroll
    for (int p = 0; p < 8; p++) {
        int h = h0 + pg * 8 + p;
        if (h < 55)
            e1[(((n * 55 + d) * 55 + h) * 10 + w) * 128 + co] = fmaxf(acc[p] + bv, 0.f);
    }
}

// ---------------------------------------------------------------------------
// conv2: e1 (8,55,55,10,128) * w (5,5,1,128,64) stride (2,2,1) + b, relu
//   -> e2 (8,26,26,10,64)
// R15: 256 threads (co64 x pg4, h split 7+7+7+5) for 8 waves/SIMD latency
// hiding (was 2). Per-pg col base pg*14 (8B-aligned) -> float2 LDS reads,
// all-static register indexing. Accumulation chain per output identical to
// R14 (c0->kr->ci->kh, col = 2h+kh) -> bit-identical. XCD chunking kept.
// pg3's acc[5..6] accumulate staged zeros and are not stored.
// ---------------------------------------------------------------------------
__global__ __launch_bounds__(256) void k_conv2(const float* __restrict__ e1,
                                               const float* __restrict__ w2,
                                               const float* __restrict__ b2,
                                               float* __restrict__ e2) {
    int bid = (blockIdx.x & 7) * 260 + (blockIdx.x >> 3);  // XCD chunking
    int w = bid % 10; int tmp = bid / 10;
    int d = tmp % 26; int n = tmp / 26;

    __shared__ __align__(16) float patch[5][16][60];
    int tid = threadIdx.x;
    int co = tid & 63, pg = tid >> 6;   // pg 0..3
    int hb = pg * 7;
    int np = (pg == 3) ? 5 : 7;
    int base = pg * 14;                 // 8B-aligned LDS col base
    float bv = b2[co];
    float acc[7];
#pragma unroll
    for (int p = 0; p < 7; p++) acc[p] = bv;

    for (int c0 = 0; c0 < 128; c0 += 16) {
        __syncthreads();
        for (int idx = tid; idx < 5 * 59 * 16; idx += 256) {
            int ci = idx & 15; int t2 = idx >> 4;
            int col = t2 % 59; int kr = t2 / 59;
            float v = 0.f;
            if (col < 55)
                v = e1[(((n * 55 + d * 2 + kr) * 55 + col) * 10 + w) * 128 + c0 + ci];
            patch[kr][ci][col] = v;
        }
        __syncthreads();

        for (int kr = 0; kr < 5; kr++) {
            for (int ci0 = 0; ci0 < 16; ci0 += 4) {
                float wv[4][5];
#pragma unroll
                for (int u = 0; u < 4; u++) {
                    const float* wp = w2 + ((kr * 5) * 128 + c0 + ci0 + u) * 64 + co;
#pragma unroll
                    for (int kh = 0; kh < 5; kh++) wv[u][kh] = wp[kh * 128 * 64];
                }
#pragma unroll
                for (int u = 0; u < 4; u++) {
                    const float* pr = &patch[kr][ci0 + u][base];
                    float rr2[18];
#pragma unroll
                    for (int q = 0; q < 9; q++) {
                        float2 t2v = *(const float2*)(pr + 2 * q);
                        rr2[2 * q] = t2v.x; rr2[2 * q + 1] = t2v.y;
                    }
#pragma unroll
                    for (int kh = 0; kh < 5; kh++) {
                        float w_ = wv[u][kh];
#pragma unroll
                        for (int p = 0; p < 7; p++)
                            acc[p] += rr2[2 * p + kh] * w_;
                    }
                }
            }
        }
    }
#pragma unroll
    for (int p = 0; p < 7; p++) {
        if (p < np) {
            int h = hb + p;
            e2[(((n * 26 + d) * 26 + h) * 10 + w) * 64 + co] = fmaxf(acc[p], 0.f);
        }
    }
}

// ---------------------------------------------------------------------------
// x-conv for ConvLSTM: 3x3 SAME conv over 26x10 frames, batched over 208
// frames. in: [fr = n*26+t][r][c][CIN]; out xz: [t*8+n][r][c][COUT] (+bias)
// ---------------------------------------------------------------------------
template <int CIN, int COUT>
__global__ __launch_bounds__(COUT) void k_xconv(const float* __restrict__ in,
                                                const float* __restrict__ wx,
                                                const float* __restrict__ bias,
                                                float* __restrict__ xz) {
    int bid = blockIdx.x;
    int r = bid % 26; int fr = bid / 26;
    int n = fr / 26, t = fr % 26;

    __shared__ __align__(16) float patch[3][CIN][12];
    int tid = threadIdx.x;
    const float* inf = in + (size_t)fr * (26 * 10 * CIN);
    for (int idx = tid; idx < 3 * 12 * CIN; idx += COUT) {
        int ci = idx % CIN; int t2 = idx / CIN;
        int col = t2 % 12; int kr = t2 / 12;
        int rr = r - 1 + kr; int cc = col - 1;
        float v = 0.f;
        if (rr >= 0 && rr < 26 && cc >= 0 && cc < 10)
            v = inf[(rr * 10 + cc) * CIN + ci];
        patch[kr][ci][col] = v;
    }
    __syncthreads();

    int co = tid;
    float bv = bias[co];
    float acc[10];
#pragma unroll
    for (int c = 0; c < 10; c++) acc[c] = bv;

    for (int kr = 0; kr < 3; kr++) {
        for (int ci0 = 0; ci0 < CIN; ci0 += 4) {
            float wv[4][3];
#pragma unroll
            for (int u = 0; u < 4; u++) {
                const float* wp = wx + ((kr * 3) * CIN + ci0 + u) * COUT + co;
#pragma unroll
                for (int kc = 0; kc < 3; kc++) wv[u][kc] = wp[kc * CIN * COUT];
            }
#pragma unroll
            for (int u = 0; u < 4; u++) {
                const float4* row = (const float4*)&patch[kr][ci0 + u][0];
                float rr2[12];
#pragma unroll
                for (int q = 0; q < 3; q++) {
                    float4 t4 = row[q];
                    rr2[4 * q] = t4.x; rr2[4 * q + 1] = t4.y;
                    rr2[4 * q + 2] = t4.z; rr2[4 * q + 3] = t4.w;
                }
#pragma unroll
                for (int kc = 0; kc < 3; kc++) {
                    float w_ = wv[u][kc];
#pragma unroll
                    for (int c = 0; c < 10; c++) acc[c] += rr2[c + kc] * w_;
                }
            }
        }
    }
    float* outp = xz + ((size_t)(t * 8 + n) * 260 + r * 10) * COUT + co;
#pragma unroll
    for (int c = 0; c < 10; c++) outp[c * COUT] = acc[c];
}

// ---------------------------------------------------------------------------
// Flag reset (before each LSTM layer): flags[b*26+r] = steps completed.
// ---------------------------------------------------------------------------
__global__ void k_rst(int* __restrict__ f) {
    if (threadIdx.x < 208)
        __hip_atomic_store(f + threadIdx.x, 0, __ATOMIC_RELAXED,
                           __HIP_MEMORY_SCOPE_AGENT);
}

// ---------------------------------------------------------------------------
// ConvLSTM layer, flag-skew pipeline, spill-free scheduling. (R11, passing.)
// RELEASE flag publish; agent-scope atomic halo/publish; dedicated y buffers;
// no per-thread array live across __syncthreads() (64-VGPR cap @1024 thr).
// ---------------------------------------------------------------------------
template <int F, int QS>
__global__ __launch_bounds__(4 * F * QS) void k_lstm(const float* __restrict__ xz,
                                                     const float* __restrict__ wh,
                                                     float* __restrict__ y,
                                                     int* __restrict__ flags) {
    constexpr int C4 = 4 * F;
    constexpr int NT = 4 * F * QS;
    constexpr int CQ = F / QS;
    int bid = blockIdx.x;
    int r = bid % 26; int b = bid / 26;
    int tid = threadIdx.x;
    int co = tid & (C4 - 1);
    int q = tid / C4;
    int ci0 = q * CQ;

    __shared__ __align__(16) float patch[3][F][12];
    __shared__ float zpart[QS][10][C4];

    for (int i = tid; i < 3 * F * 12; i += NT) ((float*)patch)[i] = 0.f;
    __syncthreads();

    float creg = 0.f;
    int gc = tid / F, gf = tid % F;
    int* fl = flags + b * 26;

    for (int t = 0; t < 26; t++) {
        if (t > 0) {
            if (tid < 2) {
                int nb = (tid == 0) ? r - 1 : r + 1;
                if (nb >= 0 && nb < 26) {
                    while (__hip_atomic_load(fl + nb, __ATOMIC_RELAXED,
                                             __HIP_MEMORY_SCOPE_AGENT) < t)
                        __builtin_amdgcn_s_sleep(1);
                }
            }
            __syncthreads();

            for (int i = tid; i < 2 * 10 * F; i += NT) {
                int ci = i % F; int t2 = i / F;
                int col = t2 % 10; int s = t2 / 10;
                int kr = 2 * s; int rr = r - 1 + kr;
                float v = 0.f;
                if (rr >= 0 && rr < 26)
                    v = __hip_atomic_load(
                        &y[((((size_t)b * 26 + (t - 1)) * 26 + rr) * 10 + col) * F + ci],
                        __ATOMIC_RELAXED, __HIP_MEMORY_SCOPE_AGENT);
                patch[kr][ci][col + 1] = v;
            }
            __syncthreads();
        }

        float acc[10];
        if (q == 0) {
            const float* xp = xz + ((size_t)(t * 8 + b) * 260 + r * 10) * C4 + co;
#pragma unroll
            for (int c = 0; c < 10; c++) acc[c] = xp[c * C4];
        } else {
#pragma unroll
            for (int c = 0; c < 10; c++) acc[c] = 0.f;
        }

        if (t > 0) {
            const int krseq[3] = {1, 0, 2};
            for (int kk = 0; kk < 3; kk++) {
                const int kr = krseq[kk];
                for (int cu = 0; cu < CQ; cu += 4) {
                    float wv[4][3];
#pragma unroll
                    for (int u = 0; u < 4; u++) {
                        const float* wp = wh + ((kr * 3) * F + ci0 + cu + u) * C4 + co;
#pragma unroll
                        for (int kc = 0; kc < 3; kc++) wv[u][kc] = wp[kc * F * C4];
                    }
#pragma unroll
                    for (int u = 0; u < 4; u++) {
                        const float4* row = (const float4*)&patch[kr][ci0 + cu + u][0];
                        float rr2[12];
#pragma unroll
                        for (int v4 = 0; v4 < 3; v4++) {
                            float4 t4 = row[v4];
                            rr2[4 * v4] = t4.x; rr2[4 * v4 + 1] = t4.y;
                            rr2[4 * v4 + 2] = t4.z; rr2[4 * v4 + 3] = t4.w;
                        }
#pragma unroll
                        for (int kc = 0; kc < 3; kc++) {
                            float w_ = wv[u][kc];
#pragma unroll
                            for (int c = 0; c < 10; c++) acc[c] += rr2[c + kc] * w_;
                        }
                    }
                }
            }
        }

#pragma unroll
        for (int c = 0; c < 10; c++) zpart[q][c][co] = acc[c];
        __syncthreads();

        if (tid < 10 * F) {
            float zi = 0.f, zf = 0.f, zg = 0.f, zo = 0.f;
#pragma unroll
            for (int qq = 0; qq < QS; qq++) {
                zi += zpart[qq][gc][gf];
                zf += zpart[qq][gc][F + gf];
                zg += zpart[qq][gc][2 * F + gf];
                zo += zpart[qq][gc][3 * F + gf];
            }
            float cn = hsig(zf) * creg + hsig(zi) * tanhf(zg);
            float hn = hsig(zo) * tanhf(cn);
            creg = cn;
            __hip_atomic_store(
                &y[((((size_t)b * 26 + t) * 26 + r) * 10 + gc) * F + gf], hn,
                __ATOMIC_RELAXED, __HIP_MEMORY_SCOPE_AGENT);
            patch[1][gf][gc + 1] = hn;
        }
        __syncthreads();

        if (tid == 0)
            __hip_atomic_store(fl + r, t + 1, __ATOMIC_RELEASE,
                               __HIP_MEMORY_SCOPE_AGENT);
    }
}

// ---------------------------------------------------------------------------
// deconv1: h3 (8,26,26,10,64) *T w (5,5,1,64,128) stride (2,2,1) + b, relu
//   -> d1 (8,55,55,10,128)
// ---------------------------------------------------------------------------
__global__ __launch_bounds__(256) void k_deconv1(const float* __restrict__ h3,
                                                 const float* __restrict__ dw,
                                                 const float* __restrict__ db,
                                                 float* __restrict__ out) {
    int bid = blockIdx.x;
    int ht = bid & 1; int tmp = bid >> 1;
    int w = tmp % 10; tmp /= 10;
    int od = tmp % 55; int n = tmp / 55;

    __shared__ __align__(16) float patch[3][64][24];
    int tid = threadIdx.x;
    int odd = od & 1;
    int id0 = odd ? (od - 3) / 2 : od / 2 - 2;
    int ihb = ht * 16 - 2;
    for (int idx = tid; idx < 3 * 20 * 64; idx += 256) {
        int ci = idx & 63; int t2 = idx >> 6;
        int j = t2 % 20; int s = t2 / 20;
        int id = id0 + s; int ih = ihb + j;
        float v = 0.f;
        if (id >= 0 && id < 26 && ih >= 0 && ih < 26)
            v = h3[((((size_t)n * 26 + id) * 26 + ih) * 10 + w) * 64 + ci];
        patch[s][ci][j] = v;
    }
    __syncthreads();

    int co = tid & 127, pg = tid >> 7;
    float acc[16];
#pragma unroll
    for (int p = 0; p < 16; p++) acc[p] = 0.f;

    int nslot = odd ? 2 : 3;
    for (int s = 0; s < nslot; s++) {
        int kd = odd ? (1 + 2 * s) : 2 * s;
        for (int ci = 0; ci < 64; ci++) {
            const float* pr = &patch[s][ci][pg * 8];
            float rr2[10];
            {
                float4 t0 = *(const float4*)pr;
                float4 t1 = *(const float4*)(pr + 4);
                float2 t2v = *(const float2*)(pr + 8);
                rr2[0] = t0.x; rr2[1] = t0.y; rr2[2] = t0.z; rr2[3] = t0.w;
                rr2[4] = t1.x; rr2[5] = t1.y; rr2[6] = t1.z; rr2[7] = t1.w;
                rr2[8] = t2v.x; rr2[9] = t2v.y;
            }
            const float* wp = dw + ((kd * 5) * 64 + ci) * 128 + co;
#pragma unroll
            for (int kh = 0; kh < 5; kh++) {
                float wv = wp[kh * 64 * 128];
                const int po = kh & 1;
                const int rbase = (kh + po) >> 1;
#pragma unroll
                for (int jj = 0; jj < 8; jj++)
                    acc[po + 2 * jj] += rr2[rbase + jj] * wv;
            }
        }
    }
    float bv = db[co];
#pragma unroll
    for (int p = 0; p < 16; p++) {
        int oh = ht * 32 + pg * 16 + p;
        if (oh < 55)
            out[((((size_t)n * 55 + od) * 55 + oh) * 10 + w) * 128 + co] =
                fmaxf(acc[p] + bv, 0.f);
    }
}

// ---------------------------------------------------------------------------
// deconv2 stage A (per batch n): D[k][pix] = dot(d1n[pix][0:128], dw[k][0:128])
// Grid (119, 8): k split 16 + 7x15 -> 952 blocks.
// ---------------------------------------------------------------------------
__global__ __launch_bounds__(256) void k_dc2_gemm(const float* __restrict__ d1n,
                                                  const float* __restrict__ dw,
                                                  float* __restrict__ Dn) {
    int pix = blockIdx.x * 256 + threadIdx.x;
    bool act = pix < 30250;
    int y = blockIdx.y;
    int k0 = (y == 0) ? 0 : 16 + (y - 1) * 15;
    int kn = (y == 0) ? 16 : 15;

    float a[128];
    const float* ap = d1n + (size_t)(act ? pix : 0) * 128;
#pragma unroll
    for (int i = 0; i < 32; i++) {
        float4 v = ((const float4*)ap)[i];
        a[4 * i] = v.x; a[4 * i + 1] = v.y; a[4 * i + 2] = v.z; a[4 * i + 3] = v.w;
    }

    for (int kk = 0; kk < kn; kk++) {
        int k = k0 + kk;
        const float* wp = dw + k * 128;
        float acc0 = 0.f, acc1 = 0.f, acc2 = 0.f, acc3 = 0.f;
#pragma unroll
        for (int i = 0; i < 32; i++) {
            acc0 += a[4 * i + 0] * wp[4 * i + 0];
            acc1 += a[4 * i + 1] * wp[4 * i + 1];
            acc2 += a[4 * i + 2] * wp[4 * i + 2];
            acc3 += a[4 * i + 3] * wp[4 * i + 3];
        }
        if (act) Dn[k * 30250 + pix] = (acc0 + acc1) + (acc2 + acc3);
    }
}

// ---------------------------------------------------------------------------
// deconv2 stage B (per batch n): overlap-add gather. Grid (227, 3).
// ---------------------------------------------------------------------------
__global__ __launch_bounds__(256) void k_dc2_scatter(const float* __restrict__ Dn,
                                                     const float* __restrict__ db,
                                                     float* __restrict__ outn) {
    int od = blockIdx.x;
    int pd = od & 3, qd = od >> 2;
    float bv = db[0];
    int p0 = blockIdx.y * 768;
    int p1 = min(2270, p0 + 768);

    for (int p = p0 + threadIdx.x; p < p1; p += 256) {
        int w = p % 10, oh = p / 10;
        int ph = oh & 3, qh = oh >> 2;
        float acc = 0.f;
#pragma unroll
        for (int s = 0; s < 3; s++) {
            int kpd = pd + 4 * s; int id = qd - s;
            if (kpd <= 10 && id >= 0 && id < 55) {
                int kd = 10 - kpd;
#pragma unroll
                for (int t = 0; t < 3; t++) {
                    int kph = ph + 4 * t; int ih = qh - t;
                    if (kph <= 10 && ih >= 0 && ih < 55) {
                        int kh = 10 - kph;
                        acc += Dn[(kd * 11 + kh) * 30250 + (id * 55 + ih) * 10 + w];
                    }
                }
            }
        }
        outn[(size_t)od * 2270 + p] = fmaxf(acc + bv, 0.f);
    }
}

// ---------------------------------------------------------------------------
extern "C" void kernel_launch(void* const* d_in, const int* in_sizes, int n_in,
                              void* d_out, int out_size, void* d_ws, size_t ws_size,
                              hipStream_t stream) {
    const float* x   = (const float*)d_in[0];
    const float* c1w = (const float*)d_in[1];
    const float* c1b = (const float*)d_in[2];
    const float* c2w = (const float*)d_in[3];
    const float* c2b = (const float*)d_in[4];
    const float* l1x = (const float*)d_in[5];
    const float* l1h = (const float*)d_in[6];
    const float* l1b = (const float*)d_in[7];
    const float* l2x = (const float*)d_in[8];
    const float* l2h = (const float*)d_in[9];
    const float* l2b = (const float*)d_in[10];
    const float* l3x = (const float*)d_in[11];
    const float* l3h = (const float*)d_in[12];
    const float* l3b = (const float*)d_in[13];
    const float* d1w = (const float*)d_in[14];
    const float* d1b = (const float*)d_in[15];
    const float* d2w = (const float*)d_in[16];
    const float* d2b = (const float*)d_in[17];

    float* ws = (float*)d_ws;
    float* A  = ws;
    float* B  = A + 30976000;
    float* C  = B + 3461120;
    float* S  = C + 3461120;
    float* Y1 = A + 20000000;
    float* Y2 = A + 24000000;
    float* Y3 = C;
    float* D  = B;
    int* FL = (int*)S;
    float* OUT = (float*)d_out;

    // encoder
    k_conv1<<<17600, 256, 0, stream>>>(x, c1w, c1b, A);
    k_conv2<<<2080, 256, 0, stream>>>(A, c2w, c2b, B);

    // ConvLSTM layer 1: 64 -> 64
    k_xconv<64, 256><<<208 * 26, 256, 0, stream>>>(B, l1x, l1b, A);
    k_rst<<<1, 256, 0, stream>>>(FL);
    k_lstm<64, 4><<<208, 1024, 0, stream>>>(A, l1h, Y1, FL);

    // ConvLSTM layer 2: 64 -> 32
    k_xconv<64, 128><<<208 * 26, 128, 0, stream>>>(Y1, l2x, l2b, A);
    k_rst<<<1, 256, 0, stream>>>(FL);
    k_lstm<32, 8><<<208, 1024, 0, stream>>>(A, l2h, Y2, FL);

    // ConvLSTM layer 3: 32 -> 64
    k_xconv<32, 256><<<208 * 26, 256, 0, stream>>>(Y2, l3x, l3b, A);
    k_rst<<<1, 256, 0, stream>>>(FL);
    k_lstm<64, 4><<<208, 1024, 0, stream>>>(A, l3h, Y3, FL);

    // decoder
    k_deconv1<<<8800, 256, 0, stream>>>(Y3, d1w, d1b, A);

    // deconv2: two-stage per batch
    for (int n = 0; n < 8; n++) {
        const float* d1n = A + (size_t)n * 3872000;
        float* outn = OUT + (size_t)n * 515290;
        k_dc2_gemm<<<dim3(119, 8), 256, 0, stream>>>(d1n, d2w, D);
        k_dc2_scatter<<<dim3(227, 3), 256, 0, stream>>>(D, d2b, outn);
    }
}